// Round 2
// baseline (644.004 us; speedup 1.0000x reference)
//
#include <hip/hip_runtime.h>

#define NTOK 49
#define DIM 384
#define NH 12
#define HD 32
#define NB 2048
#define SCALE 0.17677669529663687f  // 32^-0.5

typedef __attribute__((ext_vector_type(8))) short short8;
typedef __attribute__((ext_vector_type(4))) float f32x4;
typedef __attribute__((ext_vector_type(4))) unsigned short u16x4;

static __device__ __forceinline__ unsigned short f2bf(float f) {
    union { float f; unsigned int u; } v; v.f = f;
    unsigned int r = v.u + 0x7FFFu + ((v.u >> 16) & 1u);
    return (unsigned short)(r >> 16);
}

// ---- workspace layout (bytes) ----
#define C_ELEMS (64 * 12 * 64 * 64)          // combined mask+bias, fp32, m-permuted
#define C_OFF 0
#define WTQ_OFF (C_ELEMS * 4)                // 12,582,912
#define WTQ_ELEMS (1152 * 384)               // W_qkv^T bf16 [col][k]
#define BQ_OFF (WTQ_OFF + WTQ_ELEMS * 2)     // scaled qkv bias fp32 [1152]
#define WTP_OFF (BQ_OFF + 1152 * 4)          // W_proj^T bf16 [384][384]
#define WTP_ELEMS (384 * 384)

__global__ __launch_bounds__(256) void wa_prep(
    const float* __restrict__ mask, const float* __restrict__ qkv_w,
    const float* __restrict__ qkv_b, const float* __restrict__ rpb,
    const float* __restrict__ proj_w, unsigned char* __restrict__ ws)
{
    float* Cm = (float*)(ws + C_OFF);
    unsigned short* wtq = (unsigned short*)(ws + WTQ_OFF);
    float* bq = (float*)(ws + BQ_OFF);
    unsigned short* wtp = (unsigned short*)(ws + WTP_OFF);
    const int TOT = C_ELEMS + WTQ_ELEMS + 1152 + WTP_ELEMS;
    for (int idx = blockIdx.x * 256 + threadIdx.x; idx < TOT; idx += gridDim.x * 256) {
        if (idx < C_ELEMS) {
            int mp = idx & 63, n = (idx >> 6) & 63, rest = idx >> 12;
            int h = rest % 12, w = rest / 12;
            int m = (mp >> 2) | ((mp & 3) << 4);   // un-permute: lane-friendly float4 layout
            float v = -1e30f;
            if (n < NTOK && m < NTOK) {
                int ni = n / 7, nj = n % 7, mi = m / 7, mj = m % 7;
                int ridx = (ni - mi + 6) * 13 + (nj - mj + 6);
                v = mask[(w * NTOK + n) * NTOK + m] + rpb[ridx * NH + h];
            }
            Cm[idx] = v;
        } else if (idx < C_ELEMS + WTQ_ELEMS) {
            int t = idx - C_ELEMS;
            int j = t / 384, k = t - j * 384;      // Wt[j][k] = qkv_w[k][j] (*SCALE for q cols)
            float s = (j < 384) ? SCALE : 1.0f;
            wtq[t] = f2bf(qkv_w[k * 1152 + j] * s);
        } else if (idx < C_ELEMS + WTQ_ELEMS + 1152) {
            int j = idx - C_ELEMS - WTQ_ELEMS;
            bq[j] = qkv_b[j] * ((j < 384) ? SCALE : 1.0f);
        } else {
            int t = idx - C_ELEMS - WTQ_ELEMS - 1152;
            int j = t / 384, k = t - j * 384;
            wtp[t] = f2bf(proj_w[k * 384 + j]);
        }
    }
}

// Fused per-window kernel: 4 waves, each wave owns 3 heads.
// LDS: X[64][392] + per-wave Q[64][40], K[64][40], VT[32][72], P[64][72]  = 146,432 B
__global__ __launch_bounds__(256, 1) void wa_main(
    const float* __restrict__ x, const float* __restrict__ bproj,
    const unsigned char* __restrict__ ws, float* __restrict__ out)
{
    __shared__ unsigned short X[64 * 392];
    __shared__ unsigned short Qb[4][64 * 40];
    __shared__ unsigned short Kb[4][64 * 40];
    __shared__ unsigned short VTb[4][32 * 72];
    __shared__ unsigned short Pb[4][64 * 72];

    const float* Cm = (const float*)(ws + C_OFF);
    const unsigned short* wtq = (const unsigned short*)(ws + WTQ_OFF);
    const float* bq = (const float*)(ws + BQ_OFF);
    const unsigned short* wtp = (const unsigned short*)(ws + WTP_OFF);

    const int tid = threadIdx.x;
    const int b = blockIdx.x;
    const int w64 = b & 63;          // window-in-image index for mask
    const int wv = tid >> 6;         // wave 0..3
    const int lane = tid & 63;
    const int lid = lane & 15;
    const int g = lane >> 4;

    // ---- phase 0: stage x window as bf16 into LDS, zero pad rows 49..63 ----
    const float4* xw = (const float4*)(x + (size_t)b * (NTOK * DIM));
    for (int i = tid; i < (NTOK * DIM) / 4; i += 256) {
        float4 v = xw[i];
        int row = i / 96;                    // 96 float4 per 384-col row
        int col = (i - row * 96) * 4;
        u16x4 o;
        o.x = f2bf(v.x); o.y = f2bf(v.y); o.z = f2bf(v.z); o.w = f2bf(v.w);
        *(u16x4*)&X[row * 392 + col] = o;
    }
    for (int i = tid; i < 15 * 384; i += 256) {
        int row = 49 + i / 384, col = i % 384;
        X[row * 392 + col] = 0;
    }
    __syncthreads();

    // block-private attnout scratch: this block's OWN d_out slice reinterpreted
    // as bf16. Slice = floats [b*18816, (b+1)*18816) = shorts [b*37632, +37632);
    // the 18816-short scratch occupies the first half. (R0 bug: b*18816 shorts
    // aliased block b/2's fp32 output -> cross-block race.)
    unsigned short* outw = (unsigned short*)out + (size_t)b * 37632;

    for (int hh = 0; hh < 3; hh++) {
        const int h = wv * 3 + hh;
        // ---- QKV for head h: 3 parts (q,k,v), each [64 rows]x[32 cols], K=384 ----
        for (int p = 0; p < 3; p++) {
            const int col0 = p * 384 + h * 32;
            f32x4 acc[4][2];
            float bv0 = bq[col0 + lid], bv1 = bq[col0 + 16 + lid];
            #pragma unroll
            for (int mt = 0; mt < 4; mt++) {
                acc[mt][0] = (f32x4){bv0, bv0, bv0, bv0};
                acc[mt][1] = (f32x4){bv1, bv1, bv1, bv1};
            }
            #pragma unroll
            for (int kk = 0; kk < 12; kk++) {
                short8 a[4], bf[2];
                #pragma unroll
                for (int mt = 0; mt < 4; mt++)
                    a[mt] = *(const short8*)&X[(lid + 16 * mt) * 392 + kk * 32 + g * 8];
                #pragma unroll
                for (int nt = 0; nt < 2; nt++)
                    bf[nt] = *(const short8*)(wtq + (size_t)(col0 + nt * 16 + lid) * 384 + kk * 32 + g * 8);
                #pragma unroll
                for (int mt = 0; mt < 4; mt++)
                    #pragma unroll
                    for (int nt = 0; nt < 2; nt++)
                        acc[mt][nt] = __builtin_amdgcn_mfma_f32_16x16x32_bf16(a[mt], bf[nt], acc[mt][nt], 0, 0, 0);
            }
            // store to per-wave LDS (v goes in transposed for PV B-operand)
            #pragma unroll
            for (int mt = 0; mt < 4; mt++)
                #pragma unroll
                for (int nt = 0; nt < 2; nt++)
                    #pragma unroll
                    for (int r = 0; r < 4; r++) {
                        int row = 16 * mt + g * 4 + r;
                        int c = nt * 16 + lid;
                        unsigned short bv = f2bf(acc[mt][nt][r]);
                        if (p == 0) Qb[wv][row * 40 + c] = bv;
                        else if (p == 1) Kb[wv][row * 40 + c] = bv;
                        else VTb[wv][c * 72 + row] = bv;
                    }
        }
        asm volatile("s_waitcnt lgkmcnt(0)" ::: "memory");

        // ---- S = q @ k^T  (K=32, single MFMA step) ----
        f32x4 S[4][4];
        {
            short8 a[4], bf[4];
            #pragma unroll
            for (int mt = 0; mt < 4; mt++) a[mt] = *(const short8*)&Qb[wv][(lid + 16 * mt) * 40 + g * 8];
            #pragma unroll
            for (int nt = 0; nt < 4; nt++) bf[nt] = *(const short8*)&Kb[wv][(lid + 16 * nt) * 40 + g * 8];
            #pragma unroll
            for (int mt = 0; mt < 4; mt++)
                #pragma unroll
                for (int nt = 0; nt < 4; nt++)
                    S[mt][nt] = __builtin_amdgcn_mfma_f32_16x16x32_bf16(a[mt], bf[nt], (f32x4){0.f, 0.f, 0.f, 0.f}, 0, 0, 0);
        }

        // ---- + (mask+bias), row softmax (cols spread over 16-lane groups) ----
        const float* cmh = Cm + ((size_t)(w64 * 12 + h)) * 4096;
        float rinv[4][4];
        #pragma unroll
        for (int mt = 0; mt < 4; mt++)
            #pragma unroll
            for (int r = 0; r < 4; r++) {
                int n = g * 4 + r + 16 * mt;
                float4 cv = *(const float4*)(cmh + n * 64 + lid * 4);
                float v0 = S[mt][0][r] + cv.x;
                float v1 = S[mt][1][r] + cv.y;
                float v2 = S[mt][2][r] + cv.z;
                float v3 = S[mt][3][r] + cv.w;
                float mx = fmaxf(fmaxf(v0, v1), fmaxf(v2, v3));
                mx = fmaxf(mx, __shfl_xor(mx, 1));
                mx = fmaxf(mx, __shfl_xor(mx, 2));
                mx = fmaxf(mx, __shfl_xor(mx, 4));
                mx = fmaxf(mx, __shfl_xor(mx, 8));
                v0 = __expf(v0 - mx); v1 = __expf(v1 - mx);
                v2 = __expf(v2 - mx); v3 = __expf(v3 - mx);
                float sm = v0 + v1 + v2 + v3;
                sm += __shfl_xor(sm, 1); sm += __shfl_xor(sm, 2);
                sm += __shfl_xor(sm, 4); sm += __shfl_xor(sm, 8);
                rinv[mt][r] = 1.0f / sm;
                S[mt][0][r] = v0; S[mt][1][r] = v1; S[mt][2][r] = v2; S[mt][3][r] = v3;
            }

        // ---- P (unnormalized, bf16) to LDS; O = P @ V ----
        #pragma unroll
        for (int mt = 0; mt < 4; mt++)
            #pragma unroll
            for (int r = 0; r < 4; r++) {
                int row = g * 4 + r + 16 * mt;
                #pragma unroll
                for (int nt = 0; nt < 4; nt++)
                    Pb[wv][row * 72 + nt * 16 + lid] = f2bf(S[mt][nt][r]);
            }
        asm volatile("s_waitcnt lgkmcnt(0)" ::: "memory");

        f32x4 O[4][2];
        #pragma unroll
        for (int mt = 0; mt < 4; mt++) { O[mt][0] = (f32x4){0.f,0.f,0.f,0.f}; O[mt][1] = (f32x4){0.f,0.f,0.f,0.f}; }
        #pragma unroll
        for (int half = 0; half < 2; half++) {
            short8 pa[4], vb[2];
            #pragma unroll
            for (int mt = 0; mt < 4; mt++)
                pa[mt] = *(const short8*)&Pb[wv][(lid + 16 * mt) * 72 + half * 32 + g * 8];
            #pragma unroll
            for (int dt = 0; dt < 2; dt++)
                vb[dt] = *(const short8*)&VTb[wv][(lid + 16 * dt) * 72 + half * 32 + g * 8];
            #pragma unroll
            for (int mt = 0; mt < 4; mt++)
                #pragma unroll
                for (int dt = 0; dt < 2; dt++)
                    O[mt][dt] = __builtin_amdgcn_mfma_f32_16x16x32_bf16(pa[mt], vb[dt], O[mt][dt], 0, 0, 0);
        }

        // ---- attnout (bf16) into block's d_out scratch, rows < 49 only ----
        #pragma unroll
        for (int mt = 0; mt < 4; mt++)
            #pragma unroll
            for (int dt = 0; dt < 2; dt++)
                #pragma unroll
                for (int r = 0; r < 4; r++) {
                    int row = g * 4 + r + 16 * mt;
                    if (row < NTOK)
                        outw[row * 384 + h * 32 + dt * 16 + lid] = f2bf(O[mt][dt][r] * rinv[mt][r]);
                }
    }

    __threadfence_block();
    __syncthreads();

    // ---- proj: [64x384] @ Wt_proj + b; wave owns 96 cols. Reads before barrier, stores after ----
    {
        const int c0 = wv * 96;
        f32x4 acc[4][6];
        #pragma unroll
        for (int nt = 0; nt < 6; nt++) {
            float bv = bproj[c0 + nt * 16 + lid];
            #pragma unroll
            for (int mt = 0; mt < 4; mt++) acc[mt][nt] = (f32x4){bv, bv, bv, bv};
        }
        #pragma unroll
        for (int kk = 0; kk < 12; kk++) {
            short8 a[4], bf[6];
            #pragma unroll
            for (int mt = 0; mt < 4; mt++) {
                int row = lid + 16 * mt;
                if (row > 48) row = 48;      // never read unwritten/stale bytes
                a[mt] = *(const short8*)(outw + row * 384 + kk * 32 + g * 8);
            }
            #pragma unroll
            for (int nt = 0; nt < 6; nt++)
                bf[nt] = *(const short8*)(wtp + (size_t)(c0 + nt * 16 + lid) * 384 + kk * 32 + g * 8);
            #pragma unroll
            for (int mt = 0; mt < 4; mt++)
                #pragma unroll
                for (int nt = 0; nt < 6; nt++)
                    acc[mt][nt] = __builtin_amdgcn_mfma_f32_16x16x32_bf16(a[mt], bf[nt], acc[mt][nt], 0, 0, 0);
        }
        __syncthreads();   // all attnout reads complete before in-place fp32 stores
        float* outb = out + (size_t)b * 18816;
        #pragma unroll
        for (int mt = 0; mt < 4; mt++)
            #pragma unroll
            for (int nt = 0; nt < 6; nt++)
                #pragma unroll
                for (int r = 0; r < 4; r++) {
                    int n = g * 4 + r + 16 * mt;
                    if (n < NTOK)
                        outb[n * 384 + c0 + nt * 16 + lid] = acc[mt][nt][r];
                }
    }
}

extern "C" void kernel_launch(void* const* d_in, const int* in_sizes, int n_in,
                              void* d_out, int out_size, void* d_ws, size_t ws_size,
                              hipStream_t stream) {
    const float* x      = (const float*)d_in[0];
    const float* mask   = (const float*)d_in[1];
    const float* qkv_w  = (const float*)d_in[2];
    const float* qkv_b  = (const float*)d_in[3];
    const float* rpb    = (const float*)d_in[4];
    const float* proj_w = (const float*)d_in[5];
    const float* proj_b = (const float*)d_in[6];
    unsigned char* ws = (unsigned char*)d_ws;

    wa_prep<<<dim3(2048), dim3(256), 0, stream>>>(mask, qkv_w, qkv_b, rpb, proj_w, ws);
    wa_main<<<dim3(NB), dim3(256), 0, stream>>>(x, proj_b, ws, (float*)d_out);
}